// Round 4
// baseline (651.123 us; speedup 1.0000x reference)
//
#include <hip/hip_runtime.h>

typedef __bf16 bf16x8 __attribute__((ext_vector_type(8)));
typedef float  f32x4  __attribute__((ext_vector_type(4)));

#define B_   32
#define OC   256
#define IC   256
#define HW   3136      // 56*56
#define HP   60        // padded rows (2 extra for n-tail overread)
#define WP   58
#define KTOT 2304      // 9 * 256
#define XPAD_BYTES ((size_t)B_ * HP * WP * IC * 2)   // 57,016,320

__device__ __forceinline__ void async16(const void* g, void* l) {
    __builtin_amdgcn_global_load_lds(
        (__attribute__((address_space(1))) void*)g,
        (__attribute__((address_space(3))) void*)l, 16, 0, 0);
}

// ---------------- pass 0: zero the padded border of Xpad ----------------
__global__ __launch_bounds__(256) void zero_border(__bf16* __restrict__ Xpad) {
    int t   = blockIdx.x * 256 + threadIdx.x;
    int b   = t / 11008;
    int r2  = t - b * 11008;
    int pos = r2 >> 5, iq = r2 & 31;
    int r, c;
    if (pos < 232) { int rr = pos / 58; c = pos - rr * 58; r = (rr == 0) ? 0 : (56 + rr); }
    else           { int p2 = pos - 232; r = 1 + (p2 >> 1); c = (p2 & 1) * 57; }
    uint4 z = make_uint4(0u, 0u, 0u, 0u);
    *(uint4*)(Xpad + ((size_t)b * (HP * WP) + r * WP + c) * IC + iq * 8) = z;
}

// ---------------- pass 1: NCHW fp32 -> padded NHWC bf16 ----------------
__global__ __launch_bounds__(256) void transpose_pad(
    const float* __restrict__ X, __bf16* __restrict__ Xpad) {
    int sc = blockIdx.x, icc = blockIdx.y, b = blockIdx.z;
    __shared__ float lt[64][65];
    int tid = threadIdx.x;
    {
        int ci = tid >> 2, sq = tid & 3;
        const float* src = X + (size_t)(b * IC + icc * 64 + ci) * HW + sc * 64 + sq * 16;
        float4 v0 = ((const float4*)src)[0];
        float4 v1 = ((const float4*)src)[1];
        float4 v2 = ((const float4*)src)[2];
        float4 v3 = ((const float4*)src)[3];
        float* dst = &lt[ci][sq * 16];
        ((float4*)dst)[0] = v0; ((float4*)dst)[1] = v1;
        ((float4*)dst)[2] = v2; ((float4*)dst)[3] = v3;
    }
    __syncthreads();
    {
        int p = tid >> 2, iq = tid & 3;
        int s = sc * 64 + p;
        int h = s / 56, w = s - h * 56;
        __bf16* dst = Xpad + ((size_t)b * (HP * WP) + (h + 1) * WP + (w + 1)) * IC + icc * 64 + iq * 16;
        bf16x8 v0, v1;
        #pragma unroll
        for (int j = 0; j < 8; ++j) v0[j] = (__bf16)lt[iq * 16 + j][p];
        #pragma unroll
        for (int j = 0; j < 8; ++j) v1[j] = (__bf16)lt[iq * 16 + 8 + j][p];
        *(bf16x8*)dst = v0;
        *(bf16x8*)(dst + 8) = v1;
    }
}

// ---------------- pass 2: weight synthesis -> Asyn[b][oc][tap*256+ic] bf16 ----------------
__global__ __launch_bounds__(256) void synth(
    const float* __restrict__ se, const float* __restrict__ weight,
    __bf16* __restrict__ Asyn) {
    int oc = blockIdx.x / 9, tap = blockIdx.x - oc * 9;
    int tid = threadIdx.x;
    const float* wrow = weight + ((size_t)(oc * 256 + tid) * 9 + tap) * 64;
    float4 w[16];
    #pragma unroll
    for (int i = 0; i < 16; ++i) w[i] = ((const float4*)wrow)[i];
    size_t outb = (size_t)oc * KTOT + tap * 256 + tid;
    #pragma unroll
    for (int b = 0; b < 32; ++b) {
        const float4* sb = (const float4*)(se + b * 64);  // uniform -> s_load
        float acc = 0.f;
        #pragma unroll
        for (int i = 0; i < 16; ++i) {
            float4 s4 = sb[i];
            acc += w[i].x * s4.x + w[i].y * s4.y + w[i].z * s4.z + w[i].w * s4.w;
        }
        Asyn[(size_t)b * OC * KTOT + outb] = (__bf16)acc;
    }
}

// ---------------- pass 3: per-sample implicit GEMM, barrier-free K-loop ----------------
// Wave-private double-buffered A staging in LDS (each wave stages exactly the
// rows it reads -> NO __syncthreads in the K-loop). B-frags load directly
// global->VGPR (16 contiguous 64B lines per load, L1/L2-hit). Sync is one
// explicit s_waitcnt vmcnt(4) per iter: at that point the only VMEM older
// than {bv(k), stageA(k+1)} is stageA(k), so vmcnt(4) guarantees stageA(k)
// landed regardless of whether the scheduler sinks the bv loads.
__global__ __launch_bounds__(256, 3) void conv_mfma(
    const __bf16* __restrict__ Asyn, const __bf16* __restrict__ Xpad,
    const float* __restrict__ bias, float* __restrict__ Out) {
    const int i = blockIdx.x;
    const int xcd = i & 7, slot = i >> 3;        // slot 0..199
    const int bg = slot / 50, r2 = slot - bg * 50;
    const int b = xcd + 8 * bg;                  // 4 samples per XCD, phased
    const int mtile = r2 & 1, ntile = r2 >> 1;   // 2 x 25

    __shared__ __bf16 Al[4][2][2048];            // [wave][buf][64 rows x 32 k]
    const int tid = threadIdx.x;
    const int wid = tid >> 6, lane = tid & 63;
    const int wm = wid & 1, wn = wid >> 1;
    const int fr = lane & 15, fq = lane >> 4;

    // A stage pointers: wave stages its own 64 rows (wm half), 64 B/row (BK=32).
    // async16 chunk c: lane -> row c*16 + (lane>>2), granule lane&3 (16 B).
    const __bf16* ap[4];
    #pragma unroll
    for (int c = 0; c < 4; ++c) {
        const int row = mtile * 128 + wm * 64 + c * 16 + (lane >> 2);
        ap[c] = Asyn + (size_t)(b * OC + row) * KTOT + (lane & 3) * 8;
    }
    // B gather bases: n = ntile*128 + wn*64 + i2*16 + fr ; k-granule fq*8.
    // max n = 3199 -> h<=57, +kh<=59 < HP: in-bounds (zeros for n>=3136).
    const __bf16* xb = Xpad + (size_t)b * (HP * WP) * IC;
    const __bf16* xbn[4];
    #pragma unroll
    for (int i2 = 0; i2 < 4; ++i2) {
        const int nn = ntile * 128 + wn * 64 + i2 * 16 + fr;
        const int h = nn / 56, w = nn - h * 56;
        xbn[i2] = xb + (h * WP + w) * IC + fq * 8;
    }

    f32x4 acc[4][4] = {};
    char* mybuf = (char*)&Al[wid][0][0];

    // prologue: stage k=0 into buf 0
    #pragma unroll
    for (int c = 0; c < 4; ++c) async16(ap[c], mybuf + c * 1024);

    #pragma unroll 2
    for (int k = 0; k < 72; ++k) {
        const int tap = k >> 3, icc = k & 7;
        const int kh = (tap * 11) >> 5;          // tap/3 for tap<9
        const int kw = tap - kh * 3;
        const int offB = (kh * WP + kw) * IC + icc * 32;
        bf16x8 bv[4];
        #pragma unroll
        for (int i2 = 0; i2 < 4; ++i2)
            bv[i2] = *(const bf16x8*)(xbn[i2] + offB);
        const int kn = (k < 71) ? k + 1 : 71;    // re-stage 71 harmlessly at tail
        const int offA = ((kn >> 3) << 8) + ((kn & 7) << 5);
        char* nbuf = mybuf + ((k + 1) & 1) * 4096;
        #pragma unroll
        for (int c = 0; c < 4; ++c) async16(ap[c] + offA, nbuf + c * 1024);
        __builtin_amdgcn_s_waitcnt(0x0f74);      // vmcnt(4): stageA(k) landed
        bf16x8 af[4];
        const char* rbuf = mybuf + (k & 1) * 4096;
        #pragma unroll
        for (int i2 = 0; i2 < 4; ++i2)
            af[i2] = *(const bf16x8*)(rbuf + (i2 * 16 + fr) * 64 + fq * 16);
        #pragma unroll
        for (int mi = 0; mi < 4; ++mi)
            #pragma unroll
            for (int ni = 0; ni < 4; ++ni)
                acc[mi][ni] = __builtin_amdgcn_mfma_f32_16x16x32_bf16(
                    af[mi], bv[ni], acc[mi][ni], 0, 0, 0);
    }

    // ---- store: D row = fq*4 + reg, col = fr ----
    #pragma unroll
    for (int mi = 0; mi < 4; ++mi) {
        #pragma unroll
        for (int r = 0; r < 4; ++r) {
            const int row = mtile * 128 + wm * 64 + mi * 16 + fq * 4 + r;
            const float bvv = bias[row];
            float* orow = Out + (size_t)(b * OC + row) * HW;
            #pragma unroll
            for (int ni = 0; ni < 4; ++ni) {
                const int col = ntile * 128 + wn * 64 + ni * 16 + fr;
                if (col < HW) orow[col] = acc[mi][ni][r] + bvv;
            }
        }
    }
}

extern "C" void kernel_launch(void* const* d_in, const int* in_sizes, int n_in,
                              void* d_out, int out_size, void* d_ws, size_t ws_size,
                              hipStream_t stream) {
    const float* X    = (const float*)d_in[0];   // [32,256,56,56]
    const float* se   = (const float*)d_in[1];   // [32,64]
    const float* Wt   = (const float*)d_in[2];   // [589824,64]
    const float* bias = (const float*)d_in[3];   // [256]
    __bf16* Xpad = (__bf16*)d_ws;                           // 57.0 MB
    __bf16* Asyn = (__bf16*)((char*)d_ws + XPAD_BYTES);     // 37.75 MB
    float*  Out  = (float*)d_out;

    zero_border<<<1376, 256, 0, stream>>>(Xpad);
    transpose_pad<<<dim3(49, 4, 32), 256, 0, stream>>>(X, Xpad);
    synth<<<2304, 256, 0, stream>>>(se, Wt, Asyn);
    conv_mfma<<<1600, 256, 0, stream>>>(Asyn, Xpad, bias, Out);
}